// Round 7
// baseline (108.318 us; speedup 1.0000x reference)
//
#include <hip/hip_runtime.h>
#include <math.h>

#define Bn 32
#define Cn 512
#define Hn 56
#define Wn 56
#define HW (Hn*Wn)           // 3136
#define NPLANE (Bn*Cn)       // 16384
#define F4P (HW/4)           // 784

typedef float f4 __attribute__((ext_vector_type(4)));

// ---------------------------------------------------------------------------
// Kernel A: per-(b,c) multi-scale pooling + conv chain -> scalar s0[bc]
// One block per plane (block q -> XCD q%8). Known-good from R4.
// ---------------------------------------------------------------------------
__global__ __launch_bounds__(256) void pool_conv_kernel(
    const float* __restrict__ x,
    const float* __restrict__ w1,   // [3][3][3] (ic,ky,kx)
    const float* __restrict__ w2,   // [3][3]
    float* __restrict__ s0)         // [NPLANE]
{
    __shared__ float plane[HW];     // 12544 B
    __shared__ float rs[Hn * 4];    // row-segment sums
    __shared__ float y4[16];

    const int bc = blockIdx.x;
    const int t  = threadIdx.x;
    const float* src = x + (size_t)bc * HW;

    for (int f = t; f < F4P; f += 256)
        ((f4*)plane)[f] = ((const f4*)src)[f];
    __syncthreads();

    if (t < Hn * 4) {
        const int h = t >> 2, j = t & 3;
        const float* row = plane + h * Wn + j * 14;
        float s = 0.f;
        #pragma unroll
        for (int e = 0; e < 14; ++e) s += row[e];
        rs[h * 4 + j] = s;
    }
    __syncthreads();

    if (t < 16) {
        const int i = t >> 2, j = t & 3;
        float s = 0.f;
        #pragma unroll
        for (int r = 0; r < 14; ++r) s += rs[(i * 14 + r) * 4 + j];
        y4[i * 4 + j] = s * (1.0f / 196.0f);
    }
    __syncthreads();

    if (t == 0) {
        float y2[2][2];
        #pragma unroll
        for (int p = 0; p < 2; ++p)
            #pragma unroll
            for (int q = 0; q < 2; ++q)
                y2[p][q] = 0.25f * (y4[(2*p)*4 + 2*q]   + y4[(2*p)*4 + 2*q+1]
                                  + y4[(2*p+1)*4 + 2*q] + y4[(2*p+1)*4 + 2*q+1]);
        const float y1 = 0.25f * (y2[0][0] + y2[0][1] + y2[1][0] + y2[1][1]);

        float z[2][2];
        #pragma unroll
        for (int oy = 0; oy < 2; ++oy)
            #pragma unroll
            for (int ox = 0; ox < 2; ++ox) {
                float acc = 0.f;
                #pragma unroll
                for (int ky = 0; ky < 3; ++ky)
                    #pragma unroll
                    for (int kx = 0; kx < 3; ++kx) {
                        const int yy = oy + ky, xx = ox + kx;
                        acc += y1                   * w1[0*9 + ky*3 + kx];
                        acc += y2[yy >> 1][xx >> 1] * w1[1*9 + ky*3 + kx];
                        acc += y4[yy*4 + xx]        * w1[2*9 + ky*3 + kx];
                    }
                z[oy][ox] = acc;
            }

        s0[bc] = z[0][0] * w2[1*3+1] + z[0][1] * w2[1*3+2]
               + z[1][0] * w2[2*3+1] + z[1][1] * w2[2*3+2];
    }
}

// ---------------------------------------------------------------------------
// Kernel B (fused FC + scale), XCD-AFFINE plane mapping.
// Block j = 8m + r  (r = j%8 -> XCD r) handles planes q = 64m + 8i + r,
// i=0..7 — exactly the planes whose pool blocks (block q, XCD q%8 = r) ran
// on the SAME XCD, so surviving L2 lines are local. All 8 planes lie in one
// batch (64m..64m+63 never crosses a 512 boundary). FC recomputed per block
// (33 KFLOP, negligible). nt-stores for out.
// ---------------------------------------------------------------------------
__global__ __launch_bounds__(256) void fc_scale_kernel(
    const float* __restrict__ x,
    const float* __restrict__ s0,    // [Bn*Cn]
    const float* __restrict__ fc1,   // [32][512]
    const float* __restrict__ fc2,   // [512][32]
    float* __restrict__ out)
{
    __shared__ float sv[Cn];
    __shared__ float hv[32];
    __shared__ float scl[8];

    const int j = blockIdx.x;
    const int r = j & 7;             // XCD
    const int m = j >> 3;            // 0..255
    const int b = m >> 3;            // batch = (64m)/512
    const int t = threadIdx.x;

    for (int c = t; c < Cn; c += 256) sv[c] = s0[b * Cn + c];
    __syncthreads();

    // h[rr] = relu(sum_c sv[c] * fc1[rr][c]); 8 lanes per row
    {
        const int rr = t >> 3, l8 = t & 7;
        float acc = 0.f;
        for (int c = l8; c < Cn; c += 8) acc += sv[c] * fc1[rr * Cn + c];
        acc += __shfl_xor(acc, 1);
        acc += __shfl_xor(acc, 2);
        acc += __shfl_xor(acc, 4);
        if (l8 == 0) hv[rr] = fmaxf(acc, 0.f);
    }
    __syncthreads();

    // scl[i] = sigmoid(hv . fc2[c_i]) for this block's 8 channels
    if (t < 8) {
        const int q = 64 * m + 8 * t + r;        // plane index
        const int c = q & (Cn - 1);              // channel within batch
        float acc = 0.f;
        #pragma unroll
        for (int rr = 0; rr < 32; ++rr) acc += hv[rr] * fc2[c * 32 + rr];
        scl[t] = 1.0f / (1.0f + expf(-acc));
    }
    __syncthreads();

    // scale this block's 8 planes (same-XCD L2 affinity), nt stores
    #pragma unroll
    for (int i = 0; i < 8; ++i) {
        const int q = 64 * m + 8 * i + r;
        const float sc = scl[i];
        const f4* px = (const f4*)x   + (size_t)q * F4P;
        f4*       po = (f4*)out      + (size_t)q * F4P;
        for (int f = t; f < F4P; f += 256) {
            f4 v = px[f];
            v *= sc;
            __builtin_nontemporal_store(v, po + f);
        }
    }
}

extern "C" void kernel_launch(void* const* d_in, const int* in_sizes, int n_in,
                              void* d_out, int out_size, void* d_ws, size_t ws_size,
                              hipStream_t stream) {
    const float* x   = (const float*)d_in[0];
    const float* w1  = (const float*)d_in[1];
    const float* w2  = (const float*)d_in[2];
    const float* fc1 = (const float*)d_in[3];
    const float* fc2 = (const float*)d_in[4];
    float* out = (float*)d_out;
    float* s0  = (float*)d_ws;          // [NPLANE]

    pool_conv_kernel<<<NPLANE, 256, 0, stream>>>(x, w1, w2, s0);
    fc_scale_kernel<<<NPLANE / 8, 256, 0, stream>>>(x, s0, fc1, fc2, out);
}